// Round 16
// baseline (279.369 us; speedup 1.0000x reference)
//
#include <hip/hip_runtime.h>
#include <hip/hip_fp16.h>

#define NH 4
#define N_RES 1000
#define E_RES 4000
#define N_ATOM 14000
#define E_ATOM 784000
#define MAXS 128    // src-slab slots/atom (Poisson λ=56, 128 is ~9.6σ)
#define NBRE 256    // blocks for k_re2
#define TABN 16385  // dist-bias table entries over [0,32], Δ=1/512
#define TINV 512.0f
#define NHB 256     // histogram blocks (counting-sort build)
#define EPB 3063    // edges per histogram block (256*3063 >= E_ATOM)

#define PROJ2_BLKS 219                 // 64 atoms/block (219*64 >= 14000)
#define RLB_BLKS (E_RES / 4)           // 1000
#define TAB_BLKS ((TABN + 255) / 256)  // 65

typedef float f32x4 __attribute__((ext_vector_type(4)));

__device__ __forceinline__ unsigned enc_f(float f) {
  unsigned u = __float_as_uint(f);
  return (u & 0x80000000u) ? ~u : (u | 0x80000000u);
}
__device__ __forceinline__ float dec_f(unsigned e) {
  unsigned u = (e & 0x80000000u) ? (e & 0x7FFFFFFFu) : ~e;
  return __uint_as_float(u);
}

// dot of 8 fp16 pairs packed in two float4-sized registers
__device__ __forceinline__ float dot8h(float4 a, float4 b) {
  const __half2* pa = (const __half2*)&a;
  const __half2* pb = (const __half2*)&b;
  float acc = 0.f;
#pragma unroll
  for (int k = 0; k < 4; ++k) {
    float2 fa = __half22float2(pa[k]);
    float2 fb = __half22float2(pb[k]);
    acc += fa.x * fb.x + fa.y * fb.y;
  }
  return acc;
}

// ---- per-block src histogram (LDS, packed u16) + coords4 pad --------------
__global__ __launch_bounds__(256) void k_hist(const int* __restrict__ cei,
                                              const float* __restrict__ co,
                                              unsigned* __restrict__ ghistP,
                                              f32x4* __restrict__ coords4) {
  __shared__ unsigned lhist[N_ATOM / 2];  // packed 2x u16, 28KB
  int b = blockIdx.x, t = threadIdx.x;
  for (int j = t; j < N_ATOM / 2; j += 256) lhist[j] = 0u;
  __syncthreads();
  int e0 = b * EPB, e1 = e0 + EPB;
  if (e1 > E_ATOM) e1 = E_ATOM;
  for (int e = e0 + t; e < e1; e += 256) {
    int src = cei[E_ATOM + e];
    atomicAdd(&lhist[src >> 1], (src & 1) ? 65536u : 1u);
  }
  // pad coords to float4 while histogram atomics drain
  for (int a = b * 256 + t; a < N_ATOM; a += NHB * 256) {
    f32x4 c = {co[a * 3 + 0], co[a * 3 + 1], co[a * 3 + 2], 0.f};
    coords4[a] = c;
  }
  __syncthreads();
  unsigned* gh = ghistP + (size_t)b * (N_ATOM / 2);
  for (int j = t; j < N_ATOM / 2; j += 256) gh[j] = lhist[j];
}

// ---- fused front end: LDS-staged proj (fp16 out) + rlb + dist table -------
__global__ __launch_bounds__(256) void kA2(
    const float* __restrict__ af, const float* __restrict__ wq,
    const float* __restrict__ bq, const float* __restrict__ wkv,
    const float* __restrict__ bkv, __half* __restrict__ Qah,
    __half* __restrict__ Kah, __half* __restrict__ Vah,
    const float* __restrict__ ref_, const float* __restrict__ nf,
    const int* __restrict__ rei, const float* __restrict__ w1,
    const float* __restrict__ b1, const float* __restrict__ w2,
    const float* __restrict__ b2, float* __restrict__ rlb,
    const float* __restrict__ rw1, const float* __restrict__ rb1,
    const float* __restrict__ rw2, const float* __restrict__ rb2,
    const float* __restrict__ rw3, const float* __restrict__ rb3,
    f32x4* __restrict__ tab) {
  __shared__ float smem[4096];  // proj: swq[1024]|swkv[2048]|saf[1024]
  __shared__ float hid[4][16];  // rlb
  int b = blockIdx.x;
  int t = threadIdx.x;
  if (b < PROJ2_BLKS) {
    float* swq = smem;
    float* swkv = smem + 1024;
    float* saf = smem + 3072;
    for (int j = t; j < 1024; j += 256) swq[j] = wq[j];
    for (int j = t; j < 2048; j += 256) swkv[j] = wkv[j];
    int a0 = b * 64;
    for (int j = t; j < 1024; j += 256) {
      int gi = a0 * 16 + j;
      saf[j] = (gi < N_ATOM * 16) ? af[gi] : 0.f;
    }
    __syncthreads();
#pragma unroll
    for (int k = 0; k < 48; ++k) {
      int idx = t + k * 256;  // 12288 outputs: 64 atoms x 192
      int al = idx / 192, j = idx % 192;
      if (a0 + al >= N_ATOM) continue;
      const float* arow = &saf[al * 16];
      if (j < 64) {
        float acc = bq[j];
#pragma unroll
        for (int i = 0; i < 16; ++i) acc += arow[i] * swq[i * 64 + j];
        Qah[(size_t)(a0 + al) * 64 + j] = __float2half_rn(acc);
      } else if (j < 128) {
        int jj = j - 64;
        int col = ((jj >> 4) << 5) + (jj & 15);  // head h, k half
        float acc = bkv[col];
#pragma unroll
        for (int i = 0; i < 16; ++i) acc += arow[i] * swkv[i * 128 + col];
        Kah[(size_t)(a0 + al) * 64 + jj] = __float2half_rn(acc);
      } else {
        int jj = j - 128;
        int col = ((jj >> 4) << 5) + 16 + (jj & 15);  // head h, v half
        float acc = bkv[col];
#pragma unroll
        for (int i = 0; i < 16; ++i) acc += arow[i] * swkv[i * 128 + col];
        Vah[(size_t)(a0 + al) * 64 + jj] = __float2half_rn(acc);
      }
    }
  } else if (b < PROJ2_BLKS + RLB_BLKS) {
    int sub = t >> 6, l = t & 63;
    int r = (b - PROJ2_BLKS) * 4 + sub;
    int r0 = rei[r], r1 = rei[E_RES + r];
    int j = l >> 2, pq = l & 3;
    float acc = 0.f;
    for (int i = pq; i < 320; i += 4) {
      float cc;
      if (i < 64) cc = ref_[r * 64 + i];
      else if (i < 192) cc = nf[r0 * 128 + (i - 64)];
      else cc = nf[r1 * 128 + (i - 192)];
      acc += cc * w1[i * 16 + j];
    }
    acc += __shfl_xor(acc, 1);
    acc += __shfl_xor(acc, 2);
    if (pq == 0) hid[sub][j] = fmaxf(acc + b1[j], 0.f);
    __syncthreads();
    if (l < 4) {
      float o = b2[l];
#pragma unroll
      for (int jj = 0; jj < 16; ++jj) o += hid[sub][jj] * w2[jj * 4 + l];
      rlb[r * 4 + l] = o;
    }
  } else {
    int i = (b - PROJ2_BLKS - RLB_BLKS) * 256 + t;
    if (i < TABN) {
      float d = (float)i * (1.0f / TINV);
      float rb[16], h1[16], h2[16];
      const float step = 20.0f / 15.0f;
      const float inv_sigma = 1.0f / 1.25f;
#pragma unroll
      for (int jj = 0; jj < 16; ++jj) {
        float tt = (d - jj * step) * inv_sigma;
        rb[jj] = __expf(-tt * tt);
      }
#pragma unroll
      for (int k = 0; k < 16; ++k) {
        float acc = rb1[k];
#pragma unroll
        for (int jj = 0; jj < 16; ++jj) acc += rb[jj] * rw1[jj * 16 + k];
        h1[k] = fmaxf(acc, 0.f);
      }
#pragma unroll
      for (int k = 0; k < 16; ++k) {
        float acc = rb2[k];
#pragma unroll
        for (int jj = 0; jj < 16; ++jj) acc += h1[jj] * rw2[jj * 16 + k];
        h2[k] = fmaxf(acc, 0.f);
      }
      f32x4 o;
#pragma unroll
      for (int h = 0; h < NH; ++h) {
        float acc = rb3[h];
#pragma unroll
        for (int jj = 0; jj < 16; ++jj) acc += h2[jj] * rw3[jj * 4 + h];
        o[h] = acc;
      }
      tab[i] = o;
    }
  }
}

// ---- per-src exclusive scan over hist blocks (u16 in/out, no atomics) -----
__global__ __launch_bounds__(256) void k_ofs(const unsigned* __restrict__ ghistP,
                                             unsigned short* __restrict__ ofs16,
                                             int* __restrict__ cnt_src) {
  int s = blockIdx.x * blockDim.x + threadIdx.x;
  if (s >= N_ATOM) return;
  int half = s >> 1;
  unsigned sel = (s & 1) ? 16 : 0;
  int run = 0;
#pragma unroll 8
  for (int b = 0; b < NHB; ++b) {
    int v = (int)((ghistP[(size_t)b * (N_ATOM / 2) + half] >> sel) & 0xFFFFu);
    ofs16[(size_t)b * N_ATOM + s] = (unsigned short)run;
    run += v;
  }
  cnt_src[s] = (run > MAXS) ? MAXS : run;
}

// ---- scatter into slab: slot = LDS base+rank, plain stores ----------------
__global__ __launch_bounds__(256) void k_scat(
    const int* __restrict__ cei, const int* __restrict__ aer,
    const unsigned* __restrict__ ofs16P, unsigned* __restrict__ pay) {
  __shared__ int lbase[N_ATOM];  // 56KB: this block's exclusive bases
  int b = blockIdx.x, t = threadIdx.x;
  const unsigned* orow = ofs16P + (size_t)b * (N_ATOM / 2);
  for (int j = t; j < N_ATOM / 2; j += 256) {
    unsigned v = orow[j];
    lbase[2 * j] = (int)(v & 0xFFFFu);
    lbase[2 * j + 1] = (int)(v >> 16);
  }
  __syncthreads();
  int e0 = b * EPB, e1 = e0 + EPB;
  if (e1 > E_ATOM) e1 = E_ATOM;
  for (int e = e0 + t; e < e1; e += 256) {
    int src = cei[E_ATOM + e];
    int dst = cei[e];
    int re = aer[e];
    int slot = atomicAdd(&lbase[src], 1);
    if (slot < MAXS)
      pay[(size_t)src * MAXS + slot] = (unsigned)dst | ((unsigned)re << 16);
  }
}

// ---- per-edge R (lane-owns-edge, fp16 Q/K) + per-atom softmax m,s ---------
__global__ __launch_bounds__(256) void k_edgeR(
    const int* __restrict__ cnt_src, const unsigned* __restrict__ pay,
    const f32x4* __restrict__ coords4, const __half* __restrict__ Qah,
    const __half* __restrict__ Kah, const float* __restrict__ rlb,
    const f32x4* __restrict__ tab, float* __restrict__ R_slab,
    f32x4* __restrict__ msm, f32x4* __restrict__ mss) {
  int l = threadIdx.x & 63;
  int a = blockIdx.x * 4 + (threadIdx.x >> 6);
  int n = cnt_src[a];
  if (n > MAXS) n = MAXS;
  size_t base = (size_t)a * MAXS;
  f32x4 ac = coords4[a];
  const float4* qp = (const float4*)(Qah + (size_t)a * 64);  // 8x16B row
  bool a0 = l < n, a1 = l + 64 < n;
  f32x4 R0, R1;
#pragma unroll
  for (int sl = 0; sl < 2; ++sl) {
    bool act = sl ? a1 : a0;
    f32x4 Rv = {-3.0e38f, -3.0e38f, -3.0e38f, -3.0e38f};
    if (act) {
      int s = l + sl * 64;
      unsigned pr = pay[base + s];
      int dst = (int)(pr & 0xFFFFu);
      int re = (int)(pr >> 16);
      f32x4 c4 = coords4[dst];
      float vx = c4[0] - ac[0] + 1e-8f;
      float vy = c4[1] - ac[1] + 1e-8f;
      float vz = c4[2] - ac[2] + 1e-8f;
      float d = sqrtf(vx * vx + vy * vy + vz * vz);
      float x = d * TINV;
      int i = (int)x;
      if (i > TABN - 2) i = TABN - 2;
      float fr = x - (float)i;
      f32x4 t0 = tab[i], t1 = tab[i + 1];
      f32x4 adb = t0 + (t1 - t0) * fr;
      const float4* kp = (const float4*)(Kah + (size_t)dst * 64);  // 8x16B
      float4 rlb4 = *(const float4*)(rlb + re * 4);
      const float* rlbp = (const float*)&rlb4;
#pragma unroll
      for (int h = 0; h < NH; ++h) {
        float dot = dot8h(qp[h * 2 + 0], kp[h * 2 + 0]) +
                    dot8h(qp[h * 2 + 1], kp[h * 2 + 1]);
        Rv[h] = dot * 0.25f + rlbp[h] + adb[h];
      }
      __builtin_nontemporal_store(Rv, (f32x4*)(R_slab + (base + s) * 4));
    }
    if (sl) R1 = Rv; else R0 = Rv;
  }
  f32x4 mx;
#pragma unroll
  for (int h = 0; h < NH; ++h) mx[h] = fmaxf(R0[h], R1[h]);
#pragma unroll
  for (int off = 1; off < 64; off <<= 1) {
#pragma unroll
    for (int h = 0; h < NH; ++h) mx[h] = fmaxf(mx[h], __shfl_xor(mx[h], off));
  }
  f32x4 ex;
#pragma unroll
  for (int h = 0; h < NH; ++h)
    ex[h] = (a0 ? __expf(R0[h] - mx[h]) : 0.f) +
            (a1 ? __expf(R1[h] - mx[h]) : 0.f);
#pragma unroll
  for (int off = 1; off < 64; off <<= 1) {
#pragma unroll
    for (int h = 0; h < NH; ++h) ex[h] += __shfl_xor(ex[h], off);
  }
  if (l == 0) {
    msm[a] = mx;
    mss[a] = ex;
  }
}

// ---- per-re counts+sums in ONE slab pass (LDS-replicated), 256 blocks -----
__global__ __launch_bounds__(1024) void k_re2(
    const int* __restrict__ cnt_src, const unsigned* __restrict__ pay,
    const float* __restrict__ R_slab, unsigned short* __restrict__ cntg16,
    float* __restrict__ br_g) {
  __shared__ unsigned scntP[E_RES / 2];  // 8KB packed u16
  __shared__ float sbr[E_RES * 4];       // 64KB
  int tid = threadIdx.x;
  int bid = blockIdx.x;
  int wv = tid >> 6, lane = tid & 63;
  int gw = bid * 16 + wv;
  for (int j = tid; j < E_RES / 2; j += 1024) scntP[j] = 0u;
  for (int j = tid; j < E_RES * 4; j += 1024) sbr[j] = 0.f;
  __syncthreads();
  for (int a = gw; a < N_ATOM; a += NBRE * 16) {
    int n = cnt_src[a];
    if (n > MAXS) n = MAXS;
    size_t base = (size_t)a * MAXS;
    for (int i = lane; i < n; i += 64) {
      int re = (int)(pay[base + i] >> 16);
      atomicAdd(&scntP[re >> 1], (re & 1) ? 65536u : 1u);
      f32x4 r = *(const f32x4*)(R_slab + (base + i) * 4);
      atomicAdd(&sbr[re * 4 + 0], r[0]);
      atomicAdd(&sbr[re * 4 + 1], r[1]);
      atomicAdd(&sbr[re * 4 + 2], r[2]);
      atomicAdd(&sbr[re * 4 + 3], r[3]);
    }
  }
  __syncthreads();
  for (int j = tid; j < E_RES; j += 1024) {
    unsigned v = scntP[j >> 1];
    cntg16[(size_t)bid * E_RES + j] =
        (unsigned short)((j & 1) ? (v >> 16) : (v & 0xFFFFu));
  }
  for (int j = tid; j < E_RES * 4; j += 1024)
    br_g[(size_t)bid * E_RES * 4 + j] = sbr[j];
}

// ---- reduce the 256 copies -> block_r (already divided by count) ----------
__global__ __launch_bounds__(256) void k_red(
    const float* __restrict__ br_g, const unsigned short* __restrict__ cntg16,
    float* __restrict__ block_r) {
  int t = blockIdx.x * blockDim.x + threadIdx.x;
  if (t >= E_RES * 4) return;
  int r = t >> 2;
  float s = 0.f;
  int c = 0;
  for (int b = 0; b < NBRE; ++b) {
    s += br_g[(size_t)b * E_RES * 4 + t];
    c += (int)cntg16[(size_t)b * E_RES + r];
  }
  block_r[t] = s / fmaxf((float)c, 1.0f);
}

// ---- residue softmax (max, denom, beta) fully in LDS, single block --------
__global__ __launch_bounds__(1024) void k_br23(
    const float* __restrict__ block_r, const int* __restrict__ rei,
    float* __restrict__ beta) {
  __shared__ unsigned resm[N_RES * 4];
  __shared__ float ress[N_RES * 4];
  int tid = threadIdx.x;
  for (int j = tid; j < N_RES * 4; j += 1024) { resm[j] = 0u; ress[j] = 0.f; }
  __syncthreads();
  float brv[4][4];
  int r1v[4];
  for (int k = 0; k < 4; ++k) {
    int r = tid + k * 1024;
    if (r < E_RES) {
      r1v[k] = rei[E_RES + r];
#pragma unroll
      for (int h = 0; h < 4; ++h) {
        brv[k][h] = block_r[r * 4 + h];
        atomicMax(&resm[r1v[k] * 4 + h], enc_f(brv[k][h]));
      }
    }
  }
  __syncthreads();
  for (int k = 0; k < 4; ++k) {
    int r = tid + k * 1024;
    if (r < E_RES) {
#pragma unroll
      for (int h = 0; h < 4; ++h)
        atomicAdd(&ress[r1v[k] * 4 + h],
                  __expf(brv[k][h] - dec_f(resm[r1v[k] * 4 + h])));
    }
  }
  __syncthreads();
  for (int k = 0; k < 4; ++k) {
    int r = tid + k * 1024;
    if (r < E_RES) {
#pragma unroll
      for (int h = 0; h < 4; ++h)
        beta[r * 4 + h] = __expf(brv[k][h] - dec_f(resm[r1v[k] * 4 + h])) /
                          (ress[r1v[k] * 4 + h] + 1e-16f);
    }
  }
}

// ---- per src atom: single-pass weighted V (fp16) + fused output GEMM ------
__global__ __launch_bounds__(256) void k_src(
    const int* __restrict__ cnt_src, const unsigned* __restrict__ pay,
    const float* __restrict__ R_slab, const float* __restrict__ beta,
    const __half* __restrict__ Vah, const f32x4* __restrict__ msm,
    const f32x4* __restrict__ mss, const float* __restrict__ wo,
    const float* __restrict__ bo, float* __restrict__ out) {
  __shared__ float sau[4][64];
  int wv = threadIdx.x >> 6, l = threadIdx.x & 63;
  int wid = blockIdx.x * 4 + wv;
  int n = cnt_src[wid];
  if (n > MAXS) n = MAXS;
  int h = l >> 4;
  size_t rbase = (size_t)wid * MAXS;
  f32x4 m4 = msm[wid], s4 = mss[wid];
  float mh = m4[h];
  float sden = s4[h] + 1e-16f;
  float acc = 0.f;
#pragma unroll 4
  for (int i = 0; i < n; ++i) {
    unsigned pr = pay[rbase + i];
    int dst = (int)(pr & 0xFFFFu);
    int re = (int)(pr >> 16);
    float rv = R_slab[(rbase + i) * 4 + h];
    float bt = beta[re * 4 + h];
    float v = __half2float(Vah[(size_t)dst * 64 + l]);
    acc += __expf(rv - mh) * bt * v;
  }
  sau[wv][l] = acc / sden;
  __syncthreads();
  int p = l >> 4, c = l & 15;
  float part = 0.f;
#pragma unroll
  for (int jj = 0; jj < 16; ++jj)
    part += sau[wv][p * 16 + jj] * wo[(p * 16 + jj) * 16 + c];
  part += __shfl_down(part, 32);
  part += __shfl_down(part, 16);
  if (l < 16) out[wid * 16 + c] = part + bo[c];
}

extern "C" void kernel_launch(void* const* d_in, const int* in_sizes, int n_in,
                              void* d_out, int out_size, void* d_ws,
                              size_t ws_size, hipStream_t stream) {
  const float* nf   = (const float*)d_in[0];
  const float* ref_ = (const float*)d_in[1];
  const int*   rei  = (const int*)d_in[2];
  const float* af   = (const float*)d_in[3];
  const float* co   = (const float*)d_in[4];
  const int*   cei  = (const int*)d_in[5];
  const int*   aer  = (const int*)d_in[6];
  const float* rw1  = (const float*)d_in[7];
  const float* rb1  = (const float*)d_in[8];
  const float* rw2  = (const float*)d_in[9];
  const float* rb2  = (const float*)d_in[10];
  const float* rw3  = (const float*)d_in[11];
  const float* rb3  = (const float*)d_in[12];
  const float* w1   = (const float*)d_in[13];
  const float* b1   = (const float*)d_in[14];
  const float* w2   = (const float*)d_in[15];
  const float* b2   = (const float*)d_in[16];
  const float* wq   = (const float*)d_in[17];
  const float* bq   = (const float*)d_in[18];
  const float* wkv  = (const float*)d_in[19];
  const float* bkv  = (const float*)d_in[20];
  const float* wo   = (const float*)d_in[21];
  const float* bo   = (const float*)d_in[22];
  float* out = (float*)d_out;

  float* ws = (float*)d_ws;
  __half*   Qah     = (__half*)ws;                   // 896000 halves (448000 f)
  __half*   Kah     = (__half*)(ws + 448000);        // 448000 f
  __half*   Vah     = (__half*)(ws + 896000);        // 448000 f
  float*    rlb     = ws + 1344000;                  //   16000
  float*    R_slab  = ws + 1360000;                  // 7168000
  unsigned* pay     = (unsigned*)(ws + 8528000);     // 1792000
  float*    br_g    = ws + 10320000;                 // 4096000 (256*16000)
  unsigned short* cntg16 = (unsigned short*)(ws + 14416000);  // 1024000 u16
  int*      cnt_src = (int*)(ws + 14928000);         //   14000
  float*    block_r = ws + 14942000;                 //   16000
  f32x4*    tab     = (f32x4*)(ws + 14958000);       //   65544 floats
  f32x4*    msm     = (f32x4*)(ws + 15023544);       //   56000
  f32x4*    mss     = (f32x4*)(ws + 15079544);       //   56000
  f32x4*    coords4 = (f32x4*)(ws + 15135544);       //   56000
  // overlays:
  unsigned* ghistP  = (unsigned*)br_g;   // 256*7000 u32, dead before k_re2
  unsigned short* ofs16 = (unsigned short*)R_slab;  // dead before k_edgeR
  float*    beta    = (float*)Qah;       // Qah dead after k_edgeR

  k_hist<<<NHB, 256, 0, stream>>>(cei, co, ghistP, coords4);
  kA2<<<PROJ2_BLKS + RLB_BLKS + TAB_BLKS, 256, 0, stream>>>(
      af, wq, bq, wkv, bkv, Qah, Kah, Vah, ref_, nf, rei, w1, b1, w2, b2, rlb,
      rw1, rb1, rw2, rb2, rw3, rb3, tab);
  k_ofs<<<(N_ATOM + 255) / 256, 256, 0, stream>>>(ghistP, ofs16, cnt_src);
  k_scat<<<NHB, 256, 0, stream>>>(cei, aer, (const unsigned*)ofs16, pay);
  k_edgeR<<<N_ATOM / 4, 256, 0, stream>>>(cnt_src, pay, coords4, Qah, Kah,
                                          rlb, tab, R_slab, msm, mss);
  k_re2<<<NBRE, 1024, 0, stream>>>(cnt_src, pay, R_slab, cntg16, br_g);
  k_red<<<(E_RES * 4 + 255) / 256, 256, 0, stream>>>(br_g, cntg16, block_r);
  k_br23<<<1, 1024, 0, stream>>>(block_r, rei, beta);
  k_src<<<N_ATOM / 4, 256, 0, stream>>>(cnt_src, pay, R_slab, beta, Vah, msm,
                                        mss, wo, bo, out);
}

// Round 17
// 209.881 us; speedup vs baseline: 1.3311x; 1.3311x over previous
//
#include <hip/hip_runtime.h>
#include <hip/hip_fp16.h>

#define NH 4
#define N_RES 1000
#define E_RES 4000
#define N_ATOM 14000
#define E_ATOM 784000
#define MAXS 128    // src-slab slots/atom (Poisson λ=56, 128 is ~9.6σ)
#define NBRE 256    // blocks for k_re2
#define TABN 16385  // dist-bias table entries over [0,32], Δ=1/512
#define TINV 512.0f
#define NHB 256     // histogram blocks (counting-sort build)
#define EPB 3063    // edges per histogram block (256*3063 >= E_ATOM)

#define PROJ2_BLKS (N_ATOM / 16)       // 875 (16 atoms/block, LDS-staged)
#define RLB_BLKS (E_RES / 4)           // 1000
#define TAB_BLKS ((TABN + 255) / 256)  // 65

typedef float f32x4 __attribute__((ext_vector_type(4)));

__device__ __forceinline__ unsigned enc_f(float f) {
  unsigned u = __float_as_uint(f);
  return (u & 0x80000000u) ? ~u : (u | 0x80000000u);
}
__device__ __forceinline__ float dec_f(unsigned e) {
  unsigned u = (e & 0x80000000u) ? (e & 0x7FFFFFFFu) : ~e;
  return __uint_as_float(u);
}

// dot of 8 fp16 pairs packed in a float4-sized register pair
__device__ __forceinline__ float dot8h(float4 a, float4 b) {
  const __half2* pa = (const __half2*)&a;
  const __half2* pb = (const __half2*)&b;
  float acc = 0.f;
#pragma unroll
  for (int k = 0; k < 4; ++k) {
    float2 fa = __half22float2(pa[k]);
    float2 fb = __half22float2(pb[k]);
    acc += fa.x * fb.x + fa.y * fb.y;
  }
  return acc;
}

// ---- per-block src histogram (LDS, packed u16) + coords4 pad --------------
__global__ __launch_bounds__(256) void k_hist(const int* __restrict__ cei,
                                              const float* __restrict__ co,
                                              unsigned* __restrict__ ghistP,
                                              f32x4* __restrict__ coords4) {
  __shared__ unsigned lhist[N_ATOM / 2];  // packed 2x u16, 28KB
  int b = blockIdx.x, t = threadIdx.x;
  for (int j = t; j < N_ATOM / 2; j += 256) lhist[j] = 0u;
  __syncthreads();
  int e0 = b * EPB, e1 = e0 + EPB;
  if (e1 > E_ATOM) e1 = E_ATOM;
  for (int e = e0 + t; e < e1; e += 256) {
    int src = cei[E_ATOM + e];
    atomicAdd(&lhist[src >> 1], (src & 1) ? 65536u : 1u);
  }
  // pad coords to float4 while histogram atomics drain
  for (int a = b * 256 + t; a < N_ATOM; a += NHB * 256) {
    f32x4 c = {co[a * 3 + 0], co[a * 3 + 1], co[a * 3 + 2], 0.f};
    coords4[a] = c;
  }
  __syncthreads();
  unsigned* gh = ghistP + (size_t)b * (N_ATOM / 2);
  for (int j = t; j < N_ATOM / 2; j += 256) gh[j] = lhist[j];
}

// ---- fused front end: LDS-staged proj (fp16 out, 16 atoms/blk) + rlb + tab
__global__ __launch_bounds__(256) void kA2(
    const float* __restrict__ af, const float* __restrict__ wq,
    const float* __restrict__ bq, const float* __restrict__ wkv,
    const float* __restrict__ bkv, __half* __restrict__ Qah,
    __half* __restrict__ Kah, __half* __restrict__ Vah,
    const float* __restrict__ ref_, const float* __restrict__ nf,
    const int* __restrict__ rei, const float* __restrict__ w1,
    const float* __restrict__ b1, const float* __restrict__ w2,
    const float* __restrict__ b2, float* __restrict__ rlb,
    const float* __restrict__ rw1, const float* __restrict__ rb1,
    const float* __restrict__ rw2, const float* __restrict__ rb2,
    const float* __restrict__ rw3, const float* __restrict__ rb3,
    f32x4* __restrict__ tab) {
  __shared__ float smem[3328];  // proj: swq[1024]|swkv[2048]|saf[256]
  __shared__ float hid[4][16];  // rlb
  int b = blockIdx.x;
  int t = threadIdx.x;
  if (b < PROJ2_BLKS) {
    float* swq = smem;
    float* swkv = smem + 1024;
    float* saf = smem + 3072;
    for (int j = t; j < 1024; j += 256) swq[j] = wq[j];
    for (int j = t; j < 2048; j += 256) swkv[j] = wkv[j];
    int a0 = b * 16;
    saf[t] = af[a0 * 16 + t];
    __syncthreads();
#pragma unroll
    for (int k = 0; k < 12; ++k) {
      int idx = t + k * 256;  // 3072 outputs: 16 atoms x 192
      int al = idx / 192, j = idx % 192;
      const float* arow = &saf[al * 16];
      if (j < 64) {
        float acc = bq[j];
#pragma unroll
        for (int i = 0; i < 16; ++i) acc += arow[i] * swq[i * 64 + j];
        Qah[(size_t)(a0 + al) * 64 + j] = __float2half_rn(acc);
      } else if (j < 128) {
        int jj = j - 64;
        int col = ((jj >> 4) << 5) + (jj & 15);  // head h, k half
        float acc = bkv[col];
#pragma unroll
        for (int i = 0; i < 16; ++i) acc += arow[i] * swkv[i * 128 + col];
        Kah[(size_t)(a0 + al) * 64 + jj] = __float2half_rn(acc);
      } else {
        int jj = j - 128;
        int col = ((jj >> 4) << 5) + 16 + (jj & 15);  // head h, v half
        float acc = bkv[col];
#pragma unroll
        for (int i = 0; i < 16; ++i) acc += arow[i] * swkv[i * 128 + col];
        Vah[(size_t)(a0 + al) * 64 + jj] = __float2half_rn(acc);
      }
    }
  } else if (b < PROJ2_BLKS + RLB_BLKS) {
    int sub = t >> 6, l = t & 63;
    int r = (b - PROJ2_BLKS) * 4 + sub;
    int r0 = rei[r], r1 = rei[E_RES + r];
    int j = l >> 2, pq = l & 3;
    float acc = 0.f;
    for (int i = pq; i < 320; i += 4) {
      float cc;
      if (i < 64) cc = ref_[r * 64 + i];
      else if (i < 192) cc = nf[r0 * 128 + (i - 64)];
      else cc = nf[r1 * 128 + (i - 192)];
      acc += cc * w1[i * 16 + j];
    }
    acc += __shfl_xor(acc, 1);
    acc += __shfl_xor(acc, 2);
    if (pq == 0) hid[sub][j] = fmaxf(acc + b1[j], 0.f);
    __syncthreads();
    if (l < 4) {
      float o = b2[l];
#pragma unroll
      for (int jj = 0; jj < 16; ++jj) o += hid[sub][jj] * w2[jj * 4 + l];
      rlb[r * 4 + l] = o;
    }
  } else {
    int i = (b - PROJ2_BLKS - RLB_BLKS) * 256 + t;
    if (i < TABN) {
      float d = (float)i * (1.0f / TINV);
      float rb[16], h1[16], h2[16];
      const float step = 20.0f / 15.0f;
      const float inv_sigma = 1.0f / 1.25f;
#pragma unroll
      for (int jj = 0; jj < 16; ++jj) {
        float tt = (d - jj * step) * inv_sigma;
        rb[jj] = __expf(-tt * tt);
      }
#pragma unroll
      for (int k = 0; k < 16; ++k) {
        float acc = rb1[k];
#pragma unroll
        for (int jj = 0; jj < 16; ++jj) acc += rb[jj] * rw1[jj * 16 + k];
        h1[k] = fmaxf(acc, 0.f);
      }
#pragma unroll
      for (int k = 0; k < 16; ++k) {
        float acc = rb2[k];
#pragma unroll
        for (int jj = 0; jj < 16; ++jj) acc += h1[jj] * rw2[jj * 16 + k];
        h2[k] = fmaxf(acc, 0.f);
      }
      f32x4 o;
#pragma unroll
      for (int h = 0; h < NH; ++h) {
        float acc = rb3[h];
#pragma unroll
        for (int jj = 0; jj < 16; ++jj) acc += h2[jj] * rw3[jj * 4 + h];
        o[h] = acc;
      }
      tab[i] = o;
    }
  }
}

// ---- per-src exclusive scan over hist blocks (u16 in/out, no atomics) -----
__global__ __launch_bounds__(256) void k_ofs(const unsigned* __restrict__ ghistP,
                                             unsigned short* __restrict__ ofs16,
                                             int* __restrict__ cnt_src) {
  int s = blockIdx.x * blockDim.x + threadIdx.x;
  if (s >= N_ATOM) return;
  int half = s >> 1;
  unsigned sel = (s & 1) ? 16 : 0;
  int run = 0;
#pragma unroll 8
  for (int b = 0; b < NHB; ++b) {
    int v = (int)((ghistP[(size_t)b * (N_ATOM / 2) + half] >> sel) & 0xFFFFu);
    ofs16[(size_t)b * N_ATOM + s] = (unsigned short)run;
    run += v;
  }
  cnt_src[s] = (run > MAXS) ? MAXS : run;
}

// ---- scatter into slab: slot = LDS base+rank, plain stores ----------------
__global__ __launch_bounds__(256) void k_scat(
    const int* __restrict__ cei, const int* __restrict__ aer,
    const unsigned* __restrict__ ofs16P, unsigned* __restrict__ pay) {
  __shared__ int lbase[N_ATOM];  // 56KB: this block's exclusive bases
  int b = blockIdx.x, t = threadIdx.x;
  const unsigned* orow = ofs16P + (size_t)b * (N_ATOM / 2);
  for (int j = t; j < N_ATOM / 2; j += 256) {
    unsigned v = orow[j];
    lbase[2 * j] = (int)(v & 0xFFFFu);
    lbase[2 * j + 1] = (int)(v >> 16);
  }
  __syncthreads();
  int e0 = b * EPB, e1 = e0 + EPB;
  if (e1 > E_ATOM) e1 = E_ATOM;
  for (int e = e0 + t; e < e1; e += 256) {
    int src = cei[E_ATOM + e];
    int dst = cei[e];
    int re = aer[e];
    int slot = atomicAdd(&lbase[src], 1);
    if (slot < MAXS)
      pay[(size_t)src * MAXS + slot] = (unsigned)dst | ((unsigned)re << 16);
  }
}

// ---- per-edge R (lane-owns-edge, fp16 Q/K) + per-atom softmax m,s ---------
__global__ __launch_bounds__(256) void k_edgeR(
    const int* __restrict__ cnt_src, const unsigned* __restrict__ pay,
    const f32x4* __restrict__ coords4, const __half* __restrict__ Qah,
    const __half* __restrict__ Kah, const float* __restrict__ rlb,
    const f32x4* __restrict__ tab, float* __restrict__ R_slab,
    f32x4* __restrict__ msm, f32x4* __restrict__ mss) {
  int l = threadIdx.x & 63;
  int a = blockIdx.x * 4 + (threadIdx.x >> 6);
  int n = cnt_src[a];
  if (n > MAXS) n = MAXS;
  size_t base = (size_t)a * MAXS;
  f32x4 ac = coords4[a];
  const float4* qp = (const float4*)(Qah + (size_t)a * 64);  // 8x16B row
  bool a0 = l < n, a1 = l + 64 < n;
  f32x4 R0, R1;
#pragma unroll
  for (int sl = 0; sl < 2; ++sl) {
    bool act = sl ? a1 : a0;
    f32x4 Rv = {-3.0e38f, -3.0e38f, -3.0e38f, -3.0e38f};
    if (act) {
      int s = l + sl * 64;
      unsigned pr = pay[base + s];
      int dst = (int)(pr & 0xFFFFu);
      int re = (int)(pr >> 16);
      f32x4 c4 = coords4[dst];
      float vx = c4[0] - ac[0] + 1e-8f;
      float vy = c4[1] - ac[1] + 1e-8f;
      float vz = c4[2] - ac[2] + 1e-8f;
      float d = sqrtf(vx * vx + vy * vy + vz * vz);
      float x = d * TINV;
      int i = (int)x;
      if (i > TABN - 2) i = TABN - 2;
      float fr = x - (float)i;
      f32x4 t0 = tab[i], t1 = tab[i + 1];
      f32x4 adb = t0 + (t1 - t0) * fr;
      const float4* kp = (const float4*)(Kah + (size_t)dst * 64);  // 8x16B
      float4 rlb4 = *(const float4*)(rlb + re * 4);
      const float* rlbp = (const float*)&rlb4;
#pragma unroll
      for (int h = 0; h < NH; ++h) {
        float dot = dot8h(qp[h * 2 + 0], kp[h * 2 + 0]) +
                    dot8h(qp[h * 2 + 1], kp[h * 2 + 1]);
        Rv[h] = dot * 0.25f + rlbp[h] + adb[h];
      }
      __builtin_nontemporal_store(Rv, (f32x4*)(R_slab + (base + s) * 4));
    }
    if (sl) R1 = Rv; else R0 = Rv;
  }
  f32x4 mx;
#pragma unroll
  for (int h = 0; h < NH; ++h) mx[h] = fmaxf(R0[h], R1[h]);
#pragma unroll
  for (int off = 1; off < 64; off <<= 1) {
#pragma unroll
    for (int h = 0; h < NH; ++h) mx[h] = fmaxf(mx[h], __shfl_xor(mx[h], off));
  }
  f32x4 ex;
#pragma unroll
  for (int h = 0; h < NH; ++h)
    ex[h] = (a0 ? __expf(R0[h] - mx[h]) : 0.f) +
            (a1 ? __expf(R1[h] - mx[h]) : 0.f);
#pragma unroll
  for (int off = 1; off < 64; off <<= 1) {
#pragma unroll
    for (int h = 0; h < NH; ++h) ex[h] += __shfl_xor(ex[h], off);
  }
  if (l == 0) {
    msm[a] = mx;
    mss[a] = ex;
  }
}

// ---- per-re counts+sums in ONE slab pass (LDS-replicated), 256 blocks -----
__global__ __launch_bounds__(1024) void k_re2(
    const int* __restrict__ cnt_src, const unsigned* __restrict__ pay,
    const float* __restrict__ R_slab, unsigned short* __restrict__ cntg16,
    float* __restrict__ br_g) {
  __shared__ unsigned scntP[E_RES / 2];  // 8KB packed u16
  __shared__ float sbr[E_RES * 4];       // 64KB
  int tid = threadIdx.x;
  int bid = blockIdx.x;
  int wv = tid >> 6, lane = tid & 63;
  int gw = bid * 16 + wv;
  for (int j = tid; j < E_RES / 2; j += 1024) scntP[j] = 0u;
  for (int j = tid; j < E_RES * 4; j += 1024) sbr[j] = 0.f;
  __syncthreads();
  for (int a = gw; a < N_ATOM; a += NBRE * 16) {
    int n = cnt_src[a];
    if (n > MAXS) n = MAXS;
    size_t base = (size_t)a * MAXS;
    for (int i = lane; i < n; i += 64) {
      int re = (int)(pay[base + i] >> 16);
      atomicAdd(&scntP[re >> 1], (re & 1) ? 65536u : 1u);
      f32x4 r = *(const f32x4*)(R_slab + (base + i) * 4);
      atomicAdd(&sbr[re * 4 + 0], r[0]);
      atomicAdd(&sbr[re * 4 + 1], r[1]);
      atomicAdd(&sbr[re * 4 + 2], r[2]);
      atomicAdd(&sbr[re * 4 + 3], r[3]);
    }
  }
  __syncthreads();
  for (int j = tid; j < E_RES; j += 1024) {
    unsigned v = scntP[j >> 1];
    cntg16[(size_t)bid * E_RES + j] =
        (unsigned short)((j & 1) ? (v >> 16) : (v & 0xFFFFu));
  }
  for (int j = tid; j < E_RES * 4; j += 1024)
    br_g[(size_t)bid * E_RES * 4 + j] = sbr[j];
}

// ---- reduce the 256 copies -> block_r (already divided by count) ----------
__global__ __launch_bounds__(256) void k_red(
    const float* __restrict__ br_g, const unsigned short* __restrict__ cntg16,
    float* __restrict__ block_r) {
  int t = blockIdx.x * blockDim.x + threadIdx.x;
  if (t >= E_RES * 4) return;
  int r = t >> 2;
  float s = 0.f;
  int c = 0;
  for (int b = 0; b < NBRE; ++b) {
    s += br_g[(size_t)b * E_RES * 4 + t];
    c += (int)cntg16[(size_t)b * E_RES + r];
  }
  block_r[t] = s / fmaxf((float)c, 1.0f);
}

// ---- residue softmax (max, denom, beta) fully in LDS, single block --------
__global__ __launch_bounds__(1024) void k_br23(
    const float* __restrict__ block_r, const int* __restrict__ rei,
    float* __restrict__ beta) {
  __shared__ unsigned resm[N_RES * 4];
  __shared__ float ress[N_RES * 4];
  int tid = threadIdx.x;
  for (int j = tid; j < N_RES * 4; j += 1024) { resm[j] = 0u; ress[j] = 0.f; }
  __syncthreads();
  float brv[4][4];
  int r1v[4];
  for (int k = 0; k < 4; ++k) {
    int r = tid + k * 1024;
    if (r < E_RES) {
      r1v[k] = rei[E_RES + r];
#pragma unroll
      for (int h = 0; h < 4; ++h) {
        brv[k][h] = block_r[r * 4 + h];
        atomicMax(&resm[r1v[k] * 4 + h], enc_f(brv[k][h]));
      }
    }
  }
  __syncthreads();
  for (int k = 0; k < 4; ++k) {
    int r = tid + k * 1024;
    if (r < E_RES) {
#pragma unroll
      for (int h = 0; h < 4; ++h)
        atomicAdd(&ress[r1v[k] * 4 + h],
                  __expf(brv[k][h] - dec_f(resm[r1v[k] * 4 + h])));
    }
  }
  __syncthreads();
  for (int k = 0; k < 4; ++k) {
    int r = tid + k * 1024;
    if (r < E_RES) {
#pragma unroll
      for (int h = 0; h < 4; ++h)
        beta[r * 4 + h] = __expf(brv[k][h] - dec_f(resm[r1v[k] * 4 + h])) /
                          (ress[r1v[k] * 4 + h] + 1e-16f);
    }
  }
}

// ---- per src atom: single-pass weighted V (fp16) + fused output GEMM ------
__global__ __launch_bounds__(256) void k_src(
    const int* __restrict__ cnt_src, const unsigned* __restrict__ pay,
    const float* __restrict__ R_slab, const float* __restrict__ beta,
    const __half* __restrict__ Vah, const f32x4* __restrict__ msm,
    const f32x4* __restrict__ mss, const float* __restrict__ wo,
    const float* __restrict__ bo, float* __restrict__ out) {
  __shared__ float sau[4][64];
  int wv = threadIdx.x >> 6, l = threadIdx.x & 63;
  int wid = blockIdx.x * 4 + wv;
  int n = cnt_src[wid];
  if (n > MAXS) n = MAXS;
  int h = l >> 4;
  size_t rbase = (size_t)wid * MAXS;
  f32x4 m4 = msm[wid], s4 = mss[wid];
  float mh = m4[h];
  float sden = s4[h] + 1e-16f;
  float acc = 0.f;
#pragma unroll 4
  for (int i = 0; i < n; ++i) {
    unsigned pr = pay[rbase + i];
    int dst = (int)(pr & 0xFFFFu);
    int re = (int)(pr >> 16);
    float rv = R_slab[(rbase + i) * 4 + h];
    float bt = beta[re * 4 + h];
    float v = __half2float(Vah[(size_t)dst * 64 + l]);
    acc += __expf(rv - mh) * bt * v;
  }
  sau[wv][l] = acc / sden;
  __syncthreads();
  int p = l >> 4, c = l & 15;
  float part = 0.f;
#pragma unroll
  for (int jj = 0; jj < 16; ++jj)
    part += sau[wv][p * 16 + jj] * wo[(p * 16 + jj) * 16 + c];
  part += __shfl_down(part, 32);
  part += __shfl_down(part, 16);
  if (l < 16) out[wid * 16 + c] = part + bo[c];
}

extern "C" void kernel_launch(void* const* d_in, const int* in_sizes, int n_in,
                              void* d_out, int out_size, void* d_ws,
                              size_t ws_size, hipStream_t stream) {
  const float* nf   = (const float*)d_in[0];
  const float* ref_ = (const float*)d_in[1];
  const int*   rei  = (const int*)d_in[2];
  const float* af   = (const float*)d_in[3];
  const float* co   = (const float*)d_in[4];
  const int*   cei  = (const int*)d_in[5];
  const int*   aer  = (const int*)d_in[6];
  const float* rw1  = (const float*)d_in[7];
  const float* rb1  = (const float*)d_in[8];
  const float* rw2  = (const float*)d_in[9];
  const float* rb2  = (const float*)d_in[10];
  const float* rw3  = (const float*)d_in[11];
  const float* rb3  = (const float*)d_in[12];
  const float* w1   = (const float*)d_in[13];
  const float* b1   = (const float*)d_in[14];
  const float* w2   = (const float*)d_in[15];
  const float* b2   = (const float*)d_in[16];
  const float* wq   = (const float*)d_in[17];
  const float* bq   = (const float*)d_in[18];
  const float* wkv  = (const float*)d_in[19];
  const float* bkv  = (const float*)d_in[20];
  const float* wo   = (const float*)d_in[21];
  const float* bo   = (const float*)d_in[22];
  float* out = (float*)d_out;

  float* ws = (float*)d_ws;
  __half*   Qah     = (__half*)ws;                   // 896000 halves (448000 f)
  __half*   Kah     = (__half*)(ws + 448000);        // 448000 f
  __half*   Vah     = (__half*)(ws + 896000);        // 448000 f
  float*    rlb     = ws + 1344000;                  //   16000
  float*    R_slab  = ws + 1360000;                  // 7168000
  unsigned* pay     = (unsigned*)(ws + 8528000);     // 1792000
  float*    br_g    = ws + 10320000;                 // 4096000 (256*16000)
  unsigned short* cntg16 = (unsigned short*)(ws + 14416000);  // 1024000 u16
  int*      cnt_src = (int*)(ws + 14928000);         //   14000
  float*    block_r = ws + 14942000;                 //   16000
  f32x4*    tab     = (f32x4*)(ws + 14958000);       //   65544 floats
  f32x4*    msm     = (f32x4*)(ws + 15023544);       //   56000
  f32x4*    mss     = (f32x4*)(ws + 15079544);       //   56000
  f32x4*    coords4 = (f32x4*)(ws + 15135544);       //   56000
  // overlays:
  unsigned* ghistP  = (unsigned*)br_g;   // 256*7000 u32, dead before k_re2
  unsigned short* ofs16 = (unsigned short*)R_slab;  // dead before k_edgeR
  float*    beta    = (float*)Qah;       // Qah dead after k_edgeR

  k_hist<<<NHB, 256, 0, stream>>>(cei, co, ghistP, coords4);
  kA2<<<PROJ2_BLKS + RLB_BLKS + TAB_BLKS, 256, 0, stream>>>(
      af, wq, bq, wkv, bkv, Qah, Kah, Vah, ref_, nf, rei, w1, b1, w2, b2, rlb,
      rw1, rb1, rw2, rb2, rw3, rb3, tab);
  k_ofs<<<(N_ATOM + 255) / 256, 256, 0, stream>>>(ghistP, ofs16, cnt_src);
  k_scat<<<NHB, 256, 0, stream>>>(cei, aer, (const unsigned*)ofs16, pay);
  k_edgeR<<<N_ATOM / 4, 256, 0, stream>>>(cnt_src, pay, coords4, Qah, Kah,
                                          rlb, tab, R_slab, msm, mss);
  k_re2<<<NBRE, 1024, 0, stream>>>(cnt_src, pay, R_slab, cntg16, br_g);
  k_red<<<(E_RES * 4 + 255) / 256, 256, 0, stream>>>(br_g, cntg16, block_r);
  k_br23<<<1, 1024, 0, stream>>>(block_r, rei, beta);
  k_src<<<N_ATOM / 4, 256, 0, stream>>>(cnt_src, pay, R_slab, beta, Vah, msm,
                                        mss, wo, bo, out);
}